// Round 16
// baseline (70.601 us; speedup 1.0000x reference)
//
#include <hip/hip_runtime.h>

// Span masking — bit-exact JAX threefry2x32 stream (verified R5-R15).
// R16: prelude loop forced to unroll=1. The 8x-unrolled draw_pack (each
// inlining 2 threefrys + ocml f64 log) created a massive live-range bundle
// on top of tok[8] -> suspected VGPR spills to scratch + I$-cold bloat,
// the ~20us fixed residue in the R13-R15 accounting. Sequential draws have
// a small footprint (~4.2k cyc total, no spills). No semantic change.
//
// Stream (jax_threefry_partitionable=True):
//   split(key,n): keys[i] = (y0,y1) of tf(key,(0,i))
//   random_bits(key,32,(128,))[r] = y0^y1 of tf(key,(0,r))
//   _randint: (k1,k2)=split(key,2); span=2^13 -> start = bits(k2)[r] & 8191
//   _uniform: bits(key) directly
//   chain: key_{t+1}=tf(key_t,(0,0)); k2_t=tf(tf(key_t,(0,1)),(0,1));
//          kl_t=tf(key_t,(0,2)); key_0=(0,42)

static constexpr int kB = 128;
static constexpr int kS = 8192;
static constexpr int kWords = kS / 32;   // 256
static constexpr int kMaskTok = 50256;
static constexpr int kBatch = 64;
static constexpr int kTab = 2048;        // precomputed iterations (need ~704)
static constexpr int kTabBatches = kTab / kBatch;  // 32
static constexpr int kMaxBatches = 256;  // incl. fallback region

// ---------------- compile-time threefry ----------------
struct KeyPair { unsigned a, b; };

constexpr unsigned rotl_c(unsigned x, int r) {
  return (x << r) | (x >> (32 - r));
}

constexpr KeyPair tf_c(unsigned k0, unsigned k1, unsigned x0, unsigned x1) {
  unsigned ks[3] = {k0, k1, k0 ^ k1 ^ 0x1BD11BDAu};
  unsigned v0 = x0 + ks[0], v1 = x1 + ks[1];
  const int RA[4] = {13, 15, 26, 6};
  const int RB[4] = {17, 29, 16, 24};
  for (int g = 0; g < 5; ++g) {
    const int* r = (g & 1) ? RB : RA;
    for (int i = 0; i < 4; ++i) { v0 += v1; v1 = rotl_c(v1, r[i]); v1 ^= v0; }
    v0 += ks[(g + 1) % 3];
    v1 += ks[(g + 2) % 3] + (unsigned)(g + 1);
  }
  return {v0, v1};
}

struct alignas(16) Entry { unsigned k2a, k2b, kla, klb; };
static constexpr int kChunk = 256;
struct Chunk { Entry e[kChunk]; KeyPair end; };

constexpr Chunk make_chunk(KeyPair s) {
  Chunk c{};
  KeyPair key = s;
  for (int i = 0; i < kChunk; ++i) {
    KeyPair ks = tf_c(key.a, key.b, 0u, 1u);   // subkey 1 of split(key,3)
    KeyPair kl = tf_c(key.a, key.b, 0u, 2u);   // subkey 2
    KeyPair k2 = tf_c(ks.a, ks.b, 0u, 1u);     // split(ks,2)[1]
    c.e[i] = Entry{k2.a, k2.b, kl.a, kl.b};
    key = tf_c(key.a, key.b, 0u, 0u);          // chain link
  }
  c.end = key;
  return c;
}

constexpr Chunk g_c0 = make_chunk(KeyPair{0u, 42u});
constexpr Chunk g_c1 = make_chunk(g_c0.end);
constexpr Chunk g_c2 = make_chunk(g_c1.end);
constexpr Chunk g_c3 = make_chunk(g_c2.end);
constexpr Chunk g_c4 = make_chunk(g_c3.end);
constexpr Chunk g_c5 = make_chunk(g_c4.end);
constexpr Chunk g_c6 = make_chunk(g_c5.end);
constexpr Chunk g_c7 = make_chunk(g_c6.end);

struct TabAll { Entry e[kTab]; };
constexpr TabAll make_all() {
  TabAll t{};
  const Chunk* cs[8] = {&g_c0, &g_c1, &g_c2, &g_c3,
                        &g_c4, &g_c5, &g_c6, &g_c7};
  for (int c = 0; c < 8; ++c)
    for (int i = 0; i < kChunk; ++i)
      t.e[c * kChunk + i] = cs[c]->e[i];
  return t;
}

__constant__ TabAll g_tab = make_all();
__constant__ KeyPair g_chain_end = g_c7.end;   // key state at iteration kTab

// ---------------- device threefry (verified R5-R15) ----------------
__device__ __forceinline__ void tf2x32(unsigned k0, unsigned k1,
                                       unsigned x0, unsigned x1,
                                       unsigned& y0, unsigned& y1) {
  const unsigned ks0 = k0, ks1 = k1, ks2 = k0 ^ k1 ^ 0x1BD11BDAu;
  unsigned v0 = x0 + ks0;
  unsigned v1 = x1 + ks1;
#define TF_R(r) do { v0 += v1; v1 = (v1 << (r)) | (v1 >> (32 - (r))); v1 ^= v0; } while (0)
  TF_R(13); TF_R(15); TF_R(26); TF_R(6);
  v0 += ks1; v1 += ks2 + 1u;
  TF_R(17); TF_R(29); TF_R(16); TF_R(24);
  v0 += ks2; v1 += ks0 + 2u;
  TF_R(13); TF_R(15); TF_R(26); TF_R(6);
  v0 += ks0; v1 += ks1 + 3u;
  TF_R(17); TF_R(29); TF_R(16); TF_R(24);
  v0 += ks1; v1 += ks2 + 4u;
  TF_R(13); TF_R(15); TF_R(26); TF_R(6);
  v0 += ks2; v1 += ks0 + 5u;
#undef TF_R
  y0 = v0; y1 = v1;
}

// Full verified draw path: (k2,kl,r) -> packed start|len<<16 (R13, absmax 0).
__device__ __forceinline__ unsigned draw_pack(unsigned k2A, unsigned k2B,
                                              unsigned klA, unsigned klB,
                                              int r) {
  unsigned d0, d1, e0, e1;
  tf2x32(k2A, k2B, 0u, (unsigned)r, d0, d1);  // start bits
  tf2x32(klA, klB, 0u, (unsigned)r, e0, e1);  // uniform bits
  const int start = (int)((d0 ^ d1) & 8191u);
  const unsigned ubits = e0 ^ e1;
  float f = __uint_as_float((ubits >> 9) | 0x3F800000u) - 1.0f;  // exact
  float val = __fadd_rn(__fmul_rn(f, (1.0f - 1e-7f)), 1e-7f);    // no FMA
  float u = fmaxf(1e-7f, val);
  float lf = (float)log((double)u);   // correctly-rounded f32 log
  float q = __fdiv_rn(lf, -0.40546512603759765625f);
  int geo = (int)floorf(q) + 1;       // 1..40
  int len = min(geo, kS - start);     // 1..40
  return (unsigned)start | ((unsigned)len << 16);
}

// Span's bit pattern within absolute word w, given [start,end).
__device__ __forceinline__ unsigned span_bits(int start, int end, int w) {
  int lo = max(start - (w << 5), 0);
  int hi = min(end - (w << 5), 32);
  return (hi >= 32 ? 0xFFFFFFFFu : ((1u << hi) - 1u)) & (0xFFFFFFFFu << lo);
}

__global__ __launch_bounds__(256)
void span_mask_kernel(const int* __restrict__ x0tok,
                      const float* __restrict__ mask_prob,
                      int* __restrict__ out) {
  const int r = blockIdx.x;
  const int tid = threadIdx.x;

  __shared__ __align__(16) unsigned maskw[kWords];
  __shared__ unsigned dtab[kTab];   // this row's draws, start|len<<16

  // ---- epilogue loads issued FIRST: latency hides under prelude+walk ------
  const int base4 = r * (kS / 4);   // 2048 int4 per row; 8 per thread
  int4 tok[8];
#pragma unroll
  for (int k = 0; k < 8; ++k)
    tok[k] = ((const int4*)x0tok)[base4 + k * 256 + tid];

  for (int i = tid; i < kWords; i += 256) maskw[i] = 0u;

  // ---- prelude: 2048 draws, 8/thread, SEQUENTIAL (no unroll: keeps the
  // live range of one draw_pack (2 threefrys + ocml f64 log) at a time;
  // 8x unroll caused suspected VGPR spills + I$ bloat — the R15 residue) ----
#pragma unroll 1
  for (int j = 0; j < kTab / 256; ++j) {
    const int t = j * 256 + tid;
    Entry e = g_tab.e[t];
    dtab[t] = draw_pack(e.k2a, e.k2b, e.kla, e.klb, r);
  }
  __syncthreads();

  // ---- walk: wave 0 only (verified batch apply; binary-search crossing) ---
  if (tid < 64) {
    const int lane = tid;
    const int target = (int)floorf(mask_prob[r] * 8192.0f);  // *2^13 exact

    int cur = 0;
    unsigned fb0 = 0u, fb1 = 0u;   // fallback chain state (iters >= kTab)
    bool fb_init = false;
    unsigned nxt = dtab[lane];     // batch-0 draw, prefetched

    for (int b = 0; b < kMaxBatches; ++b) {
      unsigned pkc;
      if (b < kTabBatches) {
        pkc = nxt;
        if (b + 1 < kTabBatches) nxt = dtab[(b + 1) * 64 + lane];
      } else {
        // tier-3 fallback: runtime walk from baked end-state (verified R12)
        if (!fb_init) { fb0 = g_chain_end.a; fb1 = g_chain_end.b; fb_init = true; }
        unsigned mk0 = 0u, mk1 = 0u;
#pragma unroll 1
        for (int t = 0; t < kBatch; ++t) {
          const bool sel = (lane == t);
          mk0 = sel ? fb0 : mk0;
          mk1 = sel ? fb1 : mk1;
          unsigned n0, n1;
          tf2x32(fb0, fb1, 0u, 0u, n0, n1);
          fb0 = n0; fb1 = n1;
        }
        unsigned ksA, ksB, klA, klB, k2A, k2B;
        tf2x32(mk0, mk1, 0u, 1u, ksA, ksB);
        tf2x32(mk0, mk1, 0u, 2u, klA, klB);
        tf2x32(ksA, ksB, 0u, 1u, k2A, k2B);
        pkc = draw_pack(k2A, k2B, klA, klB, r);
      }
      const int start = (int)(pkc & 8191u);
      const int end = start + (int)(pkc >> 16);
      const int w0 = start >> 5, w1 = (end - 1) >> 5;  // <=3 words (len<=40)

      // optimistic apply; exact count from atomic returns (single wave:
      // DS ops execute in issue order; no barriers needed)
      uint4 pre = *(const uint4*)&maskw[4 * lane];  // pre-batch snapshot
      int d = 0;
#pragma unroll
      for (int k = 0; k < 3; ++k) {
        int w = w0 + k;
        if (w <= w1) {
          unsigned bits = span_bits(start, end, w);
          unsigned old = atomicOr(&maskw[w], bits);
          d += __popc(bits & ~old);   // Σ over ops = |new union bits| exact
        }
      }
#pragma unroll
      for (int off = 1; off < 64; off <<= 1) d += __shfl_xor(d, off);
      const int newcur = cur + d;

      if (newcur < target) { cur = newcur; continue; }  // batch fully valid

      // ---- crossing batch: binary search for smallest n, count(n)>=target.
      // Invariant: count(lo) < target <= count(hi); count(0)=cur < target.
      int lo = 0, hi = 64;
      while (hi - lo > 1) {   // 6 probes
        const int mid = (lo + hi) >> 1;
        *(uint4*)&maskw[4 * lane] = pre;   // restore snapshot
        int dm = 0;
        if (lane < mid) {
#pragma unroll
          for (int k = 0; k < 3; ++k) {
            int w = w0 + k;
            if (w <= w1) {
              unsigned bits = span_bits(start, end, w);
              unsigned old = atomicOr(&maskw[w], bits);
              dm += __popc(bits & ~old);
            }
          }
        }
#pragma unroll
        for (int off = 1; off < 64; off <<= 1) dm += __shfl_xor(dm, off);
        if (cur + dm < target) lo = mid; else hi = mid;
      }
      // final state: prior mask ∪ spans_{0..hi-1}
      *(uint4*)&maskw[4 * lane] = pre;
      if (lane < hi) {
#pragma unroll
        for (int k = 0; k < 3; ++k) {
          int w = w0 + k;
          if (w <= w1) atomicOr(&maskw[w], span_bits(start, end, w));
        }
      }
      break;  // row done
    }
  }

  __syncthreads();  // waves 1-3 waited here during the walk

  // ---- epilogue: 4-wave int4 stores (tok[] loaded at kernel start) --------
#pragma unroll
  for (int k = 0; k < 8; ++k) {
    const int i = k * 256 + tid;
    unsigned nib = maskw[i >> 3] >> ((i & 7) * 4);
    int4 xm, mm;
    mm.x = (int)(nib & 1u);        xm.x = mm.x ? kMaskTok : tok[k].x;
    mm.y = (int)((nib >> 1) & 1u); xm.y = mm.y ? kMaskTok : tok[k].y;
    mm.z = (int)((nib >> 2) & 1u); xm.z = mm.z ? kMaskTok : tok[k].z;
    mm.w = (int)((nib >> 3) & 1u); xm.w = mm.w ? kMaskTok : tok[k].w;
    ((int4*)out)[base4 + i] = xm;
    ((int4*)out)[kB * (kS / 4) + base4 + i] = mm;
  }
}

extern "C" void kernel_launch(void* const* d_in, const int* in_sizes, int n_in,
                              void* d_out, int out_size, void* d_ws, size_t ws_size,
                              hipStream_t stream) {
  const int* x0 = (const int*)d_in[0];
  const float* mp = (const float*)d_in[1];
  int* out = (int*)d_out;
  hipLaunchKernelGGL(span_mask_kernel, dim3(kB), dim3(256), 0, stream,
                     x0, mp, out);
}

// Round 17
// 67.721 us; speedup vs baseline: 1.0425x; 1.0425x over previous
//
#include <hip/hip_runtime.h>

// Span masking — bit-exact JAX threefry2x32 stream (verified R5-R16).
// R17: cold-memory mitigation. The timed graph's 256MB d_ws poison sweeps
// L2/L3 every replay, so g_tab/mask_prob reads are HBM-cold (~900cyc). Load
// all table entries in PARALLEL into registers first (one miss wave), then
// compute draws sequentially; hoist mask_prob to kernel start. kTab 2048->1024
// (measured crossing ~batch 11 of 16; tier-3 fallback keeps correctness
// unconditional) halves prelude compute + table traffic.
//
// Stream (jax_threefry_partitionable=True):
//   split(key,n): keys[i] = (y0,y1) of tf(key,(0,i))
//   random_bits(key,32,(128,))[r] = y0^y1 of tf(key,(0,r))
//   _randint: (k1,k2)=split(key,2); span=2^13 -> start = bits(k2)[r] & 8191
//   _uniform: bits(key) directly
//   chain: key_{t+1}=tf(key_t,(0,0)); k2_t=tf(tf(key_t,(0,1)),(0,1));
//          kl_t=tf(key_t,(0,2)); key_0=(0,42)

static constexpr int kB = 128;
static constexpr int kS = 8192;
static constexpr int kWords = kS / 32;   // 256
static constexpr int kMaskTok = 50256;
static constexpr int kBatch = 64;
static constexpr int kTab = 1024;        // precomputed iterations (need ~704)
static constexpr int kTabBatches = kTab / kBatch;  // 16
static constexpr int kMaxBatches = 256;  // incl. fallback region
static constexpr int kJ = kTab / 256;    // 4 draws per thread

// ---------------- compile-time threefry ----------------
struct KeyPair { unsigned a, b; };

constexpr unsigned rotl_c(unsigned x, int r) {
  return (x << r) | (x >> (32 - r));
}

constexpr KeyPair tf_c(unsigned k0, unsigned k1, unsigned x0, unsigned x1) {
  unsigned ks[3] = {k0, k1, k0 ^ k1 ^ 0x1BD11BDAu};
  unsigned v0 = x0 + ks[0], v1 = x1 + ks[1];
  const int RA[4] = {13, 15, 26, 6};
  const int RB[4] = {17, 29, 16, 24};
  for (int g = 0; g < 5; ++g) {
    const int* r = (g & 1) ? RB : RA;
    for (int i = 0; i < 4; ++i) { v0 += v1; v1 = rotl_c(v1, r[i]); v1 ^= v0; }
    v0 += ks[(g + 1) % 3];
    v1 += ks[(g + 2) % 3] + (unsigned)(g + 1);
  }
  return {v0, v1};
}

struct alignas(16) Entry { unsigned k2a, k2b, kla, klb; };
static constexpr int kChunk = 256;
struct Chunk { Entry e[kChunk]; KeyPair end; };

constexpr Chunk make_chunk(KeyPair s) {
  Chunk c{};
  KeyPair key = s;
  for (int i = 0; i < kChunk; ++i) {
    KeyPair ks = tf_c(key.a, key.b, 0u, 1u);   // subkey 1 of split(key,3)
    KeyPair kl = tf_c(key.a, key.b, 0u, 2u);   // subkey 2
    KeyPair k2 = tf_c(ks.a, ks.b, 0u, 1u);     // split(ks,2)[1]
    c.e[i] = Entry{k2.a, k2.b, kl.a, kl.b};
    key = tf_c(key.a, key.b, 0u, 0u);          // chain link
  }
  c.end = key;
  return c;
}

constexpr Chunk g_c0 = make_chunk(KeyPair{0u, 42u});
constexpr Chunk g_c1 = make_chunk(g_c0.end);
constexpr Chunk g_c2 = make_chunk(g_c1.end);
constexpr Chunk g_c3 = make_chunk(g_c2.end);

struct TabAll { Entry e[kTab]; };
constexpr TabAll make_all() {
  TabAll t{};
  const Chunk* cs[4] = {&g_c0, &g_c1, &g_c2, &g_c3};
  for (int c = 0; c < 4; ++c)
    for (int i = 0; i < kChunk; ++i)
      t.e[c * kChunk + i] = cs[c]->e[i];
  return t;
}

__constant__ TabAll g_tab = make_all();
__constant__ KeyPair g_chain_end = g_c3.end;   // key state at iteration kTab

// ---------------- device threefry (verified R5-R16) ----------------
__device__ __forceinline__ void tf2x32(unsigned k0, unsigned k1,
                                       unsigned x0, unsigned x1,
                                       unsigned& y0, unsigned& y1) {
  const unsigned ks0 = k0, ks1 = k1, ks2 = k0 ^ k1 ^ 0x1BD11BDAu;
  unsigned v0 = x0 + ks0;
  unsigned v1 = x1 + ks1;
#define TF_R(r) do { v0 += v1; v1 = (v1 << (r)) | (v1 >> (32 - (r))); v1 ^= v0; } while (0)
  TF_R(13); TF_R(15); TF_R(26); TF_R(6);
  v0 += ks1; v1 += ks2 + 1u;
  TF_R(17); TF_R(29); TF_R(16); TF_R(24);
  v0 += ks2; v1 += ks0 + 2u;
  TF_R(13); TF_R(15); TF_R(26); TF_R(6);
  v0 += ks0; v1 += ks1 + 3u;
  TF_R(17); TF_R(29); TF_R(16); TF_R(24);
  v0 += ks1; v1 += ks2 + 4u;
  TF_R(13); TF_R(15); TF_R(26); TF_R(6);
  v0 += ks2; v1 += ks0 + 5u;
#undef TF_R
  y0 = v0; y1 = v1;
}

// Full verified draw path: (k2,kl,r) -> packed start|len<<16 (R13, absmax 0).
__device__ __forceinline__ unsigned draw_pack(unsigned k2A, unsigned k2B,
                                              unsigned klA, unsigned klB,
                                              int r) {
  unsigned d0, d1, e0, e1;
  tf2x32(k2A, k2B, 0u, (unsigned)r, d0, d1);  // start bits
  tf2x32(klA, klB, 0u, (unsigned)r, e0, e1);  // uniform bits
  const int start = (int)((d0 ^ d1) & 8191u);
  const unsigned ubits = e0 ^ e1;
  float f = __uint_as_float((ubits >> 9) | 0x3F800000u) - 1.0f;  // exact
  float val = __fadd_rn(__fmul_rn(f, (1.0f - 1e-7f)), 1e-7f);    // no FMA
  float u = fmaxf(1e-7f, val);
  float lf = (float)log((double)u);   // correctly-rounded f32 log
  float q = __fdiv_rn(lf, -0.40546512603759765625f);
  int geo = (int)floorf(q) + 1;       // 1..40
  int len = min(geo, kS - start);     // 1..40
  return (unsigned)start | ((unsigned)len << 16);
}

// Span's bit pattern within absolute word w, given [start,end).
__device__ __forceinline__ unsigned span_bits(int start, int end, int w) {
  int lo = max(start - (w << 5), 0);
  int hi = min(end - (w << 5), 32);
  return (hi >= 32 ? 0xFFFFFFFFu : ((1u << hi) - 1u)) & (0xFFFFFFFFu << lo);
}

__global__ __launch_bounds__(256)
void span_mask_kernel(const int* __restrict__ x0tok,
                      const float* __restrict__ mask_prob,
                      int* __restrict__ out) {
  const int r = blockIdx.x;
  const int tid = threadIdx.x;

  __shared__ __align__(16) unsigned maskw[kWords];
  __shared__ unsigned dtab[kTab];   // this row's draws, start|len<<16

  // ---- cold loads issued FIRST (L2/L3 swept by the 256MB poison fill):
  // mask_prob scalar, all table entries (parallel), epilogue tokens.
  const float mp = mask_prob[r];
  Entry ent[kJ];
#pragma unroll
  for (int j = 0; j < kJ; ++j) ent[j] = g_tab.e[j * 256 + tid];
  const int base4 = r * (kS / 4);   // 2048 int4 per row; 8 per thread
  int4 tok[8];
#pragma unroll
  for (int k = 0; k < 8; ++k)
    tok[k] = ((const int4*)x0tok)[base4 + k * 256 + tid];

  for (int i = tid; i < kWords; i += 256) maskw[i] = 0u;

  // ---- prelude: 1024 draws, 4/thread, sequential compute (loads done) ----
#pragma unroll 1
  for (int j = 0; j < kJ; ++j) {
    const int t = j * 256 + tid;
    dtab[t] = draw_pack(ent[j].k2a, ent[j].k2b, ent[j].kla, ent[j].klb, r);
  }
  __syncthreads();

  // ---- walk: wave 0 only (verified batch apply; binary-search crossing) ---
  if (tid < 64) {
    const int lane = tid;
    const int target = (int)floorf(mp * 8192.0f);  // *2^13 exact

    int cur = 0;
    unsigned fb0 = 0u, fb1 = 0u;   // fallback chain state (iters >= kTab)
    bool fb_init = false;
    unsigned nxt = dtab[lane];     // batch-0 draw, prefetched

    for (int b = 0; b < kMaxBatches; ++b) {
      unsigned pkc;
      if (b < kTabBatches) {
        pkc = nxt;
        if (b + 1 < kTabBatches) nxt = dtab[(b + 1) * 64 + lane];
      } else {
        // tier-3 fallback: runtime walk from baked end-state (verified R12)
        if (!fb_init) { fb0 = g_chain_end.a; fb1 = g_chain_end.b; fb_init = true; }
        unsigned mk0 = 0u, mk1 = 0u;
#pragma unroll 1
        for (int t = 0; t < kBatch; ++t) {
          const bool sel = (lane == t);
          mk0 = sel ? fb0 : mk0;
          mk1 = sel ? fb1 : mk1;
          unsigned n0, n1;
          tf2x32(fb0, fb1, 0u, 0u, n0, n1);
          fb0 = n0; fb1 = n1;
        }
        unsigned ksA, ksB, klA, klB, k2A, k2B;
        tf2x32(mk0, mk1, 0u, 1u, ksA, ksB);
        tf2x32(mk0, mk1, 0u, 2u, klA, klB);
        tf2x32(ksA, ksB, 0u, 1u, k2A, k2B);
        pkc = draw_pack(k2A, k2B, klA, klB, r);
      }
      const int start = (int)(pkc & 8191u);
      const int end = start + (int)(pkc >> 16);
      const int w0 = start >> 5, w1 = (end - 1) >> 5;  // <=3 words (len<=40)

      // optimistic apply; exact count from atomic returns (single wave:
      // DS ops execute in issue order; no barriers needed)
      uint4 pre = *(const uint4*)&maskw[4 * lane];  // pre-batch snapshot
      int d = 0;
#pragma unroll
      for (int k = 0; k < 3; ++k) {
        int w = w0 + k;
        if (w <= w1) {
          unsigned bits = span_bits(start, end, w);
          unsigned old = atomicOr(&maskw[w], bits);
          d += __popc(bits & ~old);   // Σ over ops = |new union bits| exact
        }
      }
#pragma unroll
      for (int off = 1; off < 64; off <<= 1) d += __shfl_xor(d, off);
      const int newcur = cur + d;

      if (newcur < target) { cur = newcur; continue; }  // batch fully valid

      // ---- crossing batch: binary search for smallest n, count(n)>=target.
      // Invariant: count(lo) < target <= count(hi); count(0)=cur < target.
      int lo = 0, hi = 64;
      while (hi - lo > 1) {   // 6 probes
        const int mid = (lo + hi) >> 1;
        *(uint4*)&maskw[4 * lane] = pre;   // restore snapshot
        int dm = 0;
        if (lane < mid) {
#pragma unroll
          for (int k = 0; k < 3; ++k) {
            int w = w0 + k;
            if (w <= w1) {
              unsigned bits = span_bits(start, end, w);
              unsigned old = atomicOr(&maskw[w], bits);
              dm += __popc(bits & ~old);
            }
          }
        }
#pragma unroll
        for (int off = 1; off < 64; off <<= 1) dm += __shfl_xor(dm, off);
        if (cur + dm < target) lo = mid; else hi = mid;
      }
      // final state: prior mask ∪ spans_{0..hi-1}
      *(uint4*)&maskw[4 * lane] = pre;
      if (lane < hi) {
#pragma unroll
        for (int k = 0; k < 3; ++k) {
          int w = w0 + k;
          if (w <= w1) atomicOr(&maskw[w], span_bits(start, end, w));
        }
      }
      break;  // row done
    }
  }

  __syncthreads();  // waves 1-3 waited here during the walk

  // ---- epilogue: 4-wave int4 stores (tok[] loaded at kernel start) --------
#pragma unroll
  for (int k = 0; k < 8; ++k) {
    const int i = k * 256 + tid;
    unsigned nib = maskw[i >> 3] >> ((i & 7) * 4);
    int4 xm, mm;
    mm.x = (int)(nib & 1u);        xm.x = mm.x ? kMaskTok : tok[k].x;
    mm.y = (int)((nib >> 1) & 1u); xm.y = mm.y ? kMaskTok : tok[k].y;
    mm.z = (int)((nib >> 2) & 1u); xm.z = mm.z ? kMaskTok : tok[k].z;
    mm.w = (int)((nib >> 3) & 1u); xm.w = mm.w ? kMaskTok : tok[k].w;
    ((int4*)out)[base4 + i] = xm;
    ((int4*)out)[kB * (kS / 4) + base4 + i] = mm;
  }
}

extern "C" void kernel_launch(void* const* d_in, const int* in_sizes, int n_in,
                              void* d_out, int out_size, void* d_ws, size_t ws_size,
                              hipStream_t stream) {
  const int* x0 = (const int*)d_in[0];
  const float* mp = (const float*)d_in[1];
  int* out = (int*)d_out;
  hipLaunchKernelGGL(span_mask_kernel, dim3(kB), dim3(256), 0, stream,
                     x0, mp, out);
}